// Round 13
// baseline (293.711 us; speedup 1.0000x reference)
//
#include <hip/hip_runtime.h>
#include <hip/hip_bf16.h>
#include <math.h>

#define SLOPE 0.2f
typedef unsigned int uint_t;
typedef unsigned short ushort_t;
typedef __attribute__((ext_vector_type(8))) short short8;   // 8 bf16 (4 VGPRs)
typedef __attribute__((ext_vector_type(4))) float f32x4;    // MFMA accumulator

static __device__ __forceinline__ float lrelu(float v) { return v > 0.f ? v : SLOPE * v; }
static __device__ __forceinline__ ushort_t f2b(float f) {
  uint_t u = __float_as_uint(f);
  u += 0x7fffu + ((u >> 16) & 1u);
  return (ushort_t)(u >> 16);
}
static __device__ __forceinline__ float2 b2x2(uint_t u) {
  union { uint_t u; __hip_bfloat162 b; } cv;
  cv.u = u;
  return __bfloat1622float2(cv.b);
}

// ================= CSR build: atomic-free MSD bucket sort by dst =================

__device__ __forceinline__ void hist_body(const int* __restrict__ ei, int* __restrict__ ts,
                                          int E, int N, int NB, int NBUCK, int b) {
  __shared__ int h[256];
  int tid = threadIdx.x;
  h[tid] = 0;
  __syncthreads();
  int ET = E + N;
  int base = b * 4096;
#pragma unroll
  for (int j = 0; j < 16; ++j) {
    int i = base + j * 256 + tid;
    if (i < ET) {
      int d = (i < E) ? ei[E + i] : (i - E);
      atomicAdd(&h[d >> 8], 1);
    }
  }
  __syncthreads();
  if (tid < NBUCK) ts[tid * NB + b] = h[tid];
}

__device__ __forceinline__ void scan1_body(int* __restrict__ a, int* __restrict__ bsum,
                                           int L, int bid) {
  int tid = threadIdx.x;
  int base = bid * 1024 + tid * 4;
  int c0 = (base + 0 < L) ? a[base + 0] : 0;
  int c1 = (base + 1 < L) ? a[base + 1] : 0;
  int c2 = (base + 2 < L) ? a[base + 2] : 0;
  int c3 = (base + 3 < L) ? a[base + 3] : 0;
  int s = c0 + c1 + c2 + c3;
  int lane = tid & 63, wid = tid >> 6;
  int pre = s;
#pragma unroll
  for (int off = 1; off < 64; off <<= 1) {
    int t = __shfl_up(pre, off);
    if (lane >= off) pre += t;
  }
  __shared__ int wsum[4];
  if (lane == 63) wsum[wid] = pre;
  __syncthreads();
  int woff = 0;
#pragma unroll
  for (int w = 0; w < 4; ++w) woff += (w < wid) ? wsum[w] : 0;
  int excl = woff + pre - s;
  if (base + 0 < L) a[base + 0] = excl;
  if (base + 1 < L) a[base + 1] = excl + c0;
  if (base + 2 < L) a[base + 2] = excl + c0 + c1;
  if (base + 3 < L) a[base + 3] = excl + c0 + c1 + c2;
  if (tid == 255) bsum[bid] = wsum[0] + wsum[1] + wsum[2] + wsum[3];
}

__global__ __launch_bounds__(1024) void scan2(int* __restrict__ bsum, int nb) {
  __shared__ int sh[1024];
  int tid = threadIdx.x;
  int v = (tid < nb) ? bsum[tid] : 0;
  sh[tid] = v;
  __syncthreads();
  for (int off = 1; off < 1024; off <<= 1) {
    int add = (tid >= off) ? sh[tid - off] : 0;
    __syncthreads();
    sh[tid] += add;
    __syncthreads();
  }
  if (tid < nb) bsum[tid] = sh[tid] - v;
}

__global__ __launch_bounds__(256) void part_kernel(const int* __restrict__ ei,
                                                   const int* __restrict__ ts,
                                                   const int* __restrict__ bsum,
                                                   uint_t* __restrict__ tmp,
                                                   int E, int N, int NB, int NBUCK) {
  __shared__ int bin[256];
  int tid = threadIdx.x, b = blockIdx.x;
  if (tid < NBUCK) {
    int idx = tid * NB + b;
    bin[tid] = ts[idx] + bsum[idx >> 10];
  }
  __syncthreads();
  int ET = E + N;
  int base = b * 4096;
#pragma unroll
  for (int j = 0; j < 16; ++j) {
    int i = base + j * 256 + tid;
    if (i < ET) {
      int s, d;
      if (i < E) { s = ei[i]; d = ei[E + i]; } else { s = i - E; d = i - E; }
      int pos = atomicAdd(&bin[d >> 8], 1);
      tmp[pos] = ((uint_t)d << 16) | (uint_t)s;
    }
  }
}

__global__ __launch_bounds__(256) void bucket_kernel(const uint_t* __restrict__ tmp,
                                                     const int* __restrict__ ts,
                                                     const int* __restrict__ bsum,
                                                     int* __restrict__ rowptr,
                                                     int* __restrict__ esrc,
                                                     int N, int NB, int NBUCK, int ET) {
  __shared__ int h[256], pref[256], rank[256];
  __shared__ int wsum[4];
  int tid = threadIdx.x, d = blockIdx.x;
  int i0 = d * NB;
  int start = ts[i0] + bsum[i0 >> 10];
  int end = ET;
  if (d != NBUCK - 1) {
    int i1 = (d + 1) * NB;
    end = ts[i1] + bsum[i1 >> 10];
  }
  h[tid] = 0; rank[tid] = 0;
  __syncthreads();
  for (int i = start + tid; i < end; i += 256)
    atomicAdd(&h[(tmp[i] >> 16) & 255], 1);
  __syncthreads();
  int v = h[tid];
  int lane = tid & 63, wid = tid >> 6;
  int inc = v;
#pragma unroll
  for (int off = 1; off < 64; off <<= 1) {
    int t = __shfl_up(inc, off);
    if (lane >= off) inc += t;
  }
  if (lane == 63) wsum[wid] = inc;
  __syncthreads();
  int woff = 0;
#pragma unroll
  for (int w = 0; w < 4; ++w) woff += (w < wid) ? wsum[w] : 0;
  pref[tid] = woff + inc - v;
  __syncthreads();
  int idx = d * 256 + tid;
  if (idx <= N) rowptr[idx] = start + pref[tid];
  for (int i = start + tid; i < end; i += 256) {
    uint_t v2 = tmp[i];
    int low = (v2 >> 16) & 255;
    int r = atomicAdd(&rank[low], 1);
    esrc[start + pref[low] + r] = (int)(v2 & 0xffffu);
  }
}

// ========== pre-pass bodies: x->bf16 convert, WT prep ==========

// convert 8 consecutive floats per thread -> packed bf16
__device__ __forceinline__ void conv_body(const float* __restrict__ x,
                                          ushort_t* __restrict__ bx, int total8, int b) {
  int g = b * 256 + threadIdx.x;
  if (g >= total8) return;
  const float4* xp = (const float4*)(x + (long)g * 8);
  float4 v0 = xp[0], v1 = xp[1];
  uint_t p0 = (uint_t)f2b(v0.x) | ((uint_t)f2b(v0.y) << 16);
  uint_t p1 = (uint_t)f2b(v0.z) | ((uint_t)f2b(v0.w) << 16);
  uint_t p2 = (uint_t)f2b(v1.x) | ((uint_t)f2b(v1.y) << 16);
  uint_t p3 = (uint_t)f2b(v1.z) | ((uint_t)f2b(v1.w) << 16);
  uint4 pk = {p0, p1, p2, p3};
  *(uint4*)(bx + (long)g * 8) = pk;
}

// WT[c][k](bf16) from W[k][c](f32): w1 128x128, w2 128x128, w3 128x64. 5 blocks x 8192.
__device__ __forceinline__ void wprep_body(const float* __restrict__ w1,
                                           const float* __restrict__ w2,
                                           const float* __restrict__ w3,
                                           ushort_t* __restrict__ wt1,
                                           ushort_t* __restrict__ wt2,
                                           ushort_t* __restrict__ wt3, int b) {
  int tid = threadIdx.x;
#pragma unroll
  for (int j = 0; j < 32; ++j) {
    int idx = b * 8192 + j * 256 + tid;
    if (idx < 16384) {                 // w1
      int c = idx & 127, k = idx >> 7;
      wt1[c * 128 + k] = f2b(w1[idx]);
    } else if (idx < 32768) {          // w2
      int i2 = idx - 16384;
      int c = i2 & 127, k = i2 >> 7;
      wt2[c * 128 + k] = f2b(w2[i2]);
    } else if (idx < 40960) {          // w3
      int i3 = idx - 32768;
      int c = i3 & 63, k = i3 >> 6;
      wt3[c * 128 + k] = f2b(w3[i3]);
    }
  }
}

// fused pre-pass: histogram || WT prep || x convert (all input-only)
__global__ __launch_bounds__(256) void k_pre(const int* __restrict__ ei, int* __restrict__ ts,
                                             int E, int N, int NB, int NBUCK,
                                             const float* __restrict__ w1,
                                             const float* __restrict__ w2,
                                             const float* __restrict__ w3,
                                             ushort_t* __restrict__ wt1,
                                             ushort_t* __restrict__ wt2,
                                             ushort_t* __restrict__ wt3,
                                             const float* __restrict__ x,
                                             ushort_t* __restrict__ bx, int total8) {
  int bid = blockIdx.x;
  if (bid < NB) hist_body(ei, ts, E, N, NB, NBUCK, bid);
  else if (bid < NB + 5) wprep_body(w1, w2, w3, wt1, wt2, wt3, bid - NB);
  else conv_body(x, bx, total8, bid - NB - 5);
}

// ========== MFMA GEMM (bf16) + fused al epilogue ==========
// H[N,OC] = X[N,128](bf16) @ WT[OC][128](bf16). Block 256 = 4 waves x 16 rows.
// A = WT tile, B = X rows (LDS, stride 136); C/D row=q*4+reg, col=lane&15 [m89]
// => lane holds 4 consecutive out-features of X-row n; al via dot + xor16/32.

template<int OC>
__device__ __forceinline__ void mfma_body(const ushort_t* __restrict__ X,
                                          const ushort_t* __restrict__ WT,
                                          ushort_t* __restrict__ H,
                                          const float* __restrict__ a_s,
                                          const float* __restrict__ a_d,
                                          float* __restrict__ als,
                                          float* __restrict__ ald, int N, int bid) {
  const int K = 128;
  const int P = 136;
  const int MT = OC / 16;
  __shared__ ushort_t xs[64 * P];
  int tid = threadIdx.x;
  long row0 = (long)bid * 64;
#pragma unroll
  for (int i = 0; i < 4; ++i) {
    int flat = i * 256 + tid;
    int r = flat & 63, kc = flat >> 6;
    long row = row0 + r;
    long rr = row < N ? row : (long)(N - 1);
    uint4 v = *(const uint4*)(X + rr * K + kc * 8);
    *(uint4*)(xs + r * P + kc * 8) = v;
  }
  __syncthreads();
  int wave = tid >> 6, lane = tid & 63;
  int n = lane & 15, q = lane >> 4;
  int wrow = wave * 16 + n;
  f32x4 acc[MT];
#pragma unroll
  for (int t = 0; t < MT; ++t) acc[t] = (f32x4){0.f, 0.f, 0.f, 0.f};
#pragma unroll
  for (int kk = 0; kk < 4; ++kk) {
    short8 bfrag = *(const short8*)(xs + wrow * P + kk * 32 + q * 8);
#pragma unroll
    for (int t = 0; t < MT; ++t) {
      short8 afrag = *(const short8*)(WT + (t * 16 + n) * K + kk * 32 + q * 8);
      acc[t] = __builtin_amdgcn_mfma_f32_16x16x32_bf16(afrag, bfrag, acc[t], 0, 0, 0);
    }
  }
  long grow = row0 + wrow;
  bool valid = grow < N;
  float ps[4] = {0.f, 0.f, 0.f, 0.f};
  float pd[4] = {0.f, 0.f, 0.f, 0.f};
#pragma unroll
  for (int t = 0; t < MT; ++t) {
    int fb = t * 16 + q * 4;
    if (valid) {
      uint_t lo = (uint_t)f2b(acc[t][0]) | ((uint_t)f2b(acc[t][1]) << 16);
      uint_t hi = (uint_t)f2b(acc[t][2]) | ((uint_t)f2b(acc[t][3]) << 16);
      uint2 pk = {lo, hi};
      *(uint2*)(H + grow * OC + fb) = pk;
    }
    float4 sv = *(const float4*)(a_s + fb);
    float4 dv = *(const float4*)(a_d + fb);
    int hidx = (OC == 128) ? (t >> 1) : 0;
    ps[hidx] += acc[t][0] * sv.x + acc[t][1] * sv.y + acc[t][2] * sv.z + acc[t][3] * sv.w;
    pd[hidx] += acc[t][0] * dv.x + acc[t][1] * dv.y + acc[t][2] * dv.z + acc[t][3] * dv.w;
  }
  const int NH = (OC == 128) ? 4 : 1;
#pragma unroll
  for (int h = 0; h < NH; ++h) {
    ps[h] += __shfl_xor(ps[h], 16); ps[h] += __shfl_xor(ps[h], 32);
    pd[h] += __shfl_xor(pd[h], 16); pd[h] += __shfl_xor(pd[h], 32);
  }
  if (q == 0 && valid) {
    if (OC == 128) {
      float4 s4 = {ps[0], ps[1], ps[2], ps[3]};
      float4 d4 = {pd[0], pd[1], pd[2], pd[3]};
      *(float4*)(als + grow * 4) = s4;
      *(float4*)(ald + grow * 4) = d4;
    } else {
      als[grow] = ps[0];
      ald[grow] = pd[0];
    }
  }
}

template<int OC>
__global__ __launch_bounds__(256) void mfma_gemm(const ushort_t* __restrict__ X,
    const ushort_t* __restrict__ WT, ushort_t* __restrict__ H,
    const float* __restrict__ a_s, const float* __restrict__ a_d,
    float* __restrict__ als, float* __restrict__ ald, int N) {
  mfma_body<OC>(X, WT, H, a_s, a_d, als, ald, N, blockIdx.x);
}

// fused: mfma layer1 || scan1 (independent: gemm1 needs convert, scan1 needs hist)
__global__ __launch_bounds__(256) void k_gemm1_scan1(const ushort_t* __restrict__ X,
    const ushort_t* __restrict__ WT, ushort_t* __restrict__ H,
    const float* __restrict__ a_s, const float* __restrict__ a_d,
    float* __restrict__ als, float* __restrict__ ald, int N,
    int* __restrict__ ts, int* __restrict__ bsum, int SL, int gemmBlocks) {
  int bid = blockIdx.x;
  if (bid < gemmBlocks) mfma_body<128>(X, WT, H, a_s, a_d, als, ald, N, bid);
  else scan1_body(ts, bsum, SL, bid - gemmBlocks);
}

// ===== softmax aggregation (m=0), half-wave/node, 16 feats/lane =====

__global__ __launch_bounds__(256) void gat_agg128(const ushort_t* __restrict__ h,
    const float* __restrict__ als, const float* __restrict__ ald,
    const int* __restrict__ rowptr, const int* __restrict__ esrc,
    const float* __restrict__ bias, ushort_t* __restrict__ out, int N) {
  int tid = threadIdx.x;
  int n = blockIdx.x * 8 + (tid >> 5);
  int l = tid & 31;
  int slot = l >> 3, sl = l & 7, hd = sl >> 1;
  if (n >= N) return;
  int beg = rowptr[n], end = rowptr[n + 1];
  float aldv = ald[(long)n * 4 + hd];
  float den = 0.f;
  float acc[16];
#pragma unroll
  for (int j = 0; j < 16; ++j) acc[j] = 0.f;
  for (int e = beg + slot; e < end; e += 4) {
    int s = esrc[e];
    float p = __expf(lrelu(als[(long)s * 4 + hd] + aldv));
    den += p;
    const ushort_t* hp = h + (long)s * 128 + sl * 16;
    uint4 v0 = *(const uint4*)(hp);
    uint4 v1 = *(const uint4*)(hp + 8);
    uint_t vv[8] = {v0.x, v0.y, v0.z, v0.w, v1.x, v1.y, v1.z, v1.w};
#pragma unroll
    for (int j = 0; j < 8; ++j) {
      float2 f = b2x2(vv[j]);
      acc[2 * j + 0] = fmaf(p, f.x, acc[2 * j + 0]);
      acc[2 * j + 1] = fmaf(p, f.y, acc[2 * j + 1]);
    }
  }
  den += __shfl_xor(den, 8); den += __shfl_xor(den, 16);
#pragma unroll
  for (int j = 0; j < 16; ++j) {
    acc[j] += __shfl_xor(acc[j], 8);
    acc[j] += __shfl_xor(acc[j], 16);
  }
  if (slot == 0) {
    float inv = 1.f / den;
    uint_t pk[8];
#pragma unroll
    for (int j = 0; j < 8; ++j) {
      float v0 = fmaxf(fmaf(acc[2 * j + 0], inv, bias[sl * 16 + 2 * j + 0]), 0.f);
      float v1 = fmaxf(fmaf(acc[2 * j + 1], inv, bias[sl * 16 + 2 * j + 1]), 0.f);
      pk[j] = (uint_t)f2b(v0) | ((uint_t)f2b(v1) << 16);
    }
    uint4 o0 = {pk[0], pk[1], pk[2], pk[3]};
    uint4 o1 = {pk[4], pk[5], pk[6], pk[7]};
    *(uint4*)(out + (long)n * 128 + sl * 16 + 0) = o0;
    *(uint4*)(out + (long)n * 128 + sl * 16 + 8) = o1;
  }
}

__global__ __launch_bounds__(256) void gat_agg64_lsm(const ushort_t* __restrict__ h,
    const float* __restrict__ als, const float* __restrict__ ald,
    const int* __restrict__ rowptr, const int* __restrict__ esrc,
    const float* __restrict__ bias, float* __restrict__ out, int N) {
  int tid = threadIdx.x;
  int n = blockIdx.x * 8 + (tid >> 5);
  int l = tid & 31;
  int slot = l >> 2, sl = l & 3;
  if (n >= N) return;
  int beg = rowptr[n], end = rowptr[n + 1];
  float aldv = ald[n];
  float den = 0.f;
  float acc[16];
#pragma unroll
  for (int j = 0; j < 16; ++j) acc[j] = 0.f;
  for (int e = beg + slot; e < end; e += 8) {
    int s = esrc[e];
    float p = __expf(lrelu(als[s] + aldv));
    den += p;
    const ushort_t* hp = h + (long)s * 64 + sl * 16;
    uint4 v0 = *(const uint4*)(hp);
    uint4 v1 = *(const uint4*)(hp + 8);
    uint_t vv[8] = {v0.x, v0.y, v0.z, v0.w, v1.x, v1.y, v1.z, v1.w};
#pragma unroll
    for (int j = 0; j < 8; ++j) {
      float2 f = b2x2(vv[j]);
      acc[2 * j + 0] = fmaf(p, f.x, acc[2 * j + 0]);
      acc[2 * j + 1] = fmaf(p, f.y, acc[2 * j + 1]);
    }
  }
  den += __shfl_xor(den, 4); den += __shfl_xor(den, 8); den += __shfl_xor(den, 16);
#pragma unroll
  for (int j = 0; j < 16; ++j) {
    acc[j] += __shfl_xor(acc[j], 4);
    acc[j] += __shfl_xor(acc[j], 8);
    acc[j] += __shfl_xor(acc[j], 16);
  }
  if (slot == 0) {
    float inv = 1.f / den;
    float v[16];
#pragma unroll
    for (int j = 0; j < 16; ++j) v[j] = fmaf(acc[j], inv, bias[sl * 16 + j]);
    float lm = v[0];
#pragma unroll
    for (int j = 1; j < 16; ++j) lm = fmaxf(lm, v[j]);
    lm = fmaxf(lm, __shfl_xor(lm, 1));
    lm = fmaxf(lm, __shfl_xor(lm, 2));
    float es = 0.f;
#pragma unroll
    for (int j = 0; j < 16; ++j) es += __expf(v[j] - lm);
    es += __shfl_xor(es, 1);
    es += __shfl_xor(es, 2);
    float lse = lm + __logf(es);
    float* op = out + (long)n * 64 + sl * 16;
#pragma unroll
    for (int qq = 0; qq < 4; ++qq) {
      float4 o = {v[4 * qq + 0] - lse, v[4 * qq + 1] - lse, v[4 * qq + 2] - lse, v[4 * qq + 3] - lse};
      *(float4*)(op + 4 * qq) = o;
    }
  }
}

// ================= launch =================

extern "C" void kernel_launch(void* const* d_in, const int* in_sizes, int n_in,
                              void* d_out, int out_size, void* d_ws, size_t ws_size,
                              hipStream_t stream) {
  const float* x   = (const float*)d_in[0];
  const int*   ei  = (const int*)d_in[1];
  const float* w1  = (const float*)d_in[2];
  const float* as1 = (const float*)d_in[3];
  const float* ad1 = (const float*)d_in[4];
  const float* b1  = (const float*)d_in[5];
  const float* w2  = (const float*)d_in[6];
  const float* as2 = (const float*)d_in[7];
  const float* ad2 = (const float*)d_in[8];
  const float* b2  = (const float*)d_in[9];
  const float* w3  = (const float*)d_in[10];
  const float* as3 = (const float*)d_in[11];
  const float* ad3 = (const float*)d_in[12];
  const float* b3  = (const float*)d_in[13];
  float* out = (float*)d_out;

  const int N = in_sizes[0] / 128;
  const int E = in_sizes[1] / 2;
  const int ET = E + N;

  const int NB = (ET + 4095) / 4096;      // hist/part blocks
  const int NBUCK = (N + 255) >> 8;       // buckets (dst>>8)
  const int SL = NBUCK * NB;              // scan length
  const int nsb = (SL + 1023) / 1024;     // scan blocks
  const int total8 = N * 16;              // 8-float groups in x
  const int cvB = (total8 + 255) / 256;   // convert blocks

  char* ws = (char*)d_ws;
  size_t off = 0;
  auto alloc = [&](size_t bytes) -> void* {
    void* p = ws + off;
    off += (bytes + 255) & ~(size_t)255;
    return p;
  };
  ushort_t* bufX = (ushort_t*)alloc((size_t)N * 128 * 2);  // x in bf16
  ushort_t* bufA = (ushort_t*)alloc((size_t)N * 128 * 2);
  ushort_t* bufB = (ushort_t*)alloc((size_t)N * 128 * 2);
  float* als   = (float*)alloc((size_t)N * 4 * 4);
  float* ald   = (float*)alloc((size_t)N * 4 * 4);
  int* ts      = (int*)alloc((size_t)SL * 4);
  int* bsum    = (int*)alloc((size_t)1024 * 4);
  uint_t* tmp  = (uint_t*)alloc((size_t)ET * 4);
  int* rowptr  = (int*)alloc((size_t)(N + 1) * 4);
  int* esrc    = (int*)alloc((size_t)ET * 4);
  ushort_t* wt1 = (ushort_t*)alloc((size_t)128 * 128 * 2);
  ushort_t* wt2 = (ushort_t*)alloc((size_t)128 * 128 * 2);
  ushort_t* wt3 = (ushort_t*)alloc((size_t)64 * 128 * 2);

  const int ggrid = (N + 63) / 64;
  const int aggrid = (N + 7) / 8;

  // 1. pre-pass: hist || wprep(w1,w2,w3) || x->bf16
  k_pre<<<NB + 5 + cvB, 256, 0, stream>>>(ei, ts, E, N, NB, NBUCK,
                                          w1, w2, w3, wt1, wt2, wt3, x, bufX, total8);
  // 2. mfma gemm layer1 + al || scan1
  k_gemm1_scan1<<<ggrid + nsb, 256, 0, stream>>>(bufX, wt1, bufA, as1, ad1, als, ald, N,
                                                 ts, bsum, SL, ggrid);
  // 3. scan2
  scan2<<<1, 1024, 0, stream>>>(bsum, nsb);
  // 4-5. partition + per-bucket counting sort
  part_kernel<<<NB, 256, 0, stream>>>(ei, ts, bsum, tmp, E, N, NB, NBUCK);
  bucket_kernel<<<NBUCK, 256, 0, stream>>>(tmp, ts, bsum, rowptr, esrc, N, NB, NBUCK, ET);

  // 6. layer 1 aggregation
  gat_agg128<<<aggrid, 256, 0, stream>>>(bufA, als, ald, rowptr, esrc, b1, bufB, N);

  // 7-8. layer 2
  mfma_gemm<128><<<ggrid, 256, 0, stream>>>(bufB, wt2, bufA, as2, ad2, als, ald, N);
  gat_agg128<<<aggrid, 256, 0, stream>>>(bufA, als, ald, rowptr, esrc, b2, bufB, N);

  // 9-10. layer 3
  mfma_gemm<64><<<ggrid, 256, 0, stream>>>(bufB, wt3, bufA, as3, ad3, als, ald, N);
  gat_agg64_lsm<<<aggrid, 256, 0, stream>>>(bufA, als, ald, rowptr, esrc, b3, out, N);
}